// Round 3
// baseline (98.701 us; speedup 1.0000x reference)
//
#include <hip/hip_runtime.h>

// ProdLayer forward (block_size==1, single partition, accum=False):
//   element_mars[nids] = node_mars[cids].sum(axis=1)
// node_mars:    [131072, 512] f32 (268 MB — ~ LLC size)
// element_mars: [ 65600, 512] f32 (kept for rows not targeted by nids)
// nids:         [65536]       int32 (== arange; unique scatter targets)
// cids:         [65536, 4]    int32
// out:          [ 65600, 512] f32 (134 MB, write-once)
//
// Memory-bound. R1 @95us ~= full 537MB gather + 134MB write, no LLC reuse.
// R3: non-temporal output stores via native clang vector type (HIP float4
// is a class -> builtin rejects it). Goal: stop write-allocate evicting
// node_mars from the 256MB Infinity Cache.

constexpr int BATCH   = 512;
constexpr int N_PROD  = 65536;
constexpr int MAX_ELS = 65600;
constexpr int N_EDGES = 4;
constexpr int VEC     = 4;                  // float4
constexpr int LANES   = BATCH / VEC;        // 128 float4 per row
constexpr int ROWS_PER_BLOCK = 2;           // 256 threads = 2 x 128

typedef float f32x4 __attribute__((ext_vector_type(4)));

__global__ __launch_bounds__(256) void ProdLayer_69750268887705_kernel(
    const float* __restrict__ node_mars,
    const float* __restrict__ element_mars,
    const int*   __restrict__ nids,
    const int*   __restrict__ cids,
    float*       __restrict__ out)
{
    const int tid   = threadIdx.x;
    const int rsub  = tid >> 7;             // 0/1: which row of this block (wave-uniform)
    const int lane  = tid & (LANES - 1);    // float4 column index 0..127
    const int p     = blockIdx.x * ROWS_PER_BLOCK + rsub;
    if (p >= MAX_ELS) return;

    if (p < N_PROD) {
        // gather 4 child rows, sum, scatter to nids[p]
        const int out_row = nids[p];
        const int c0 = cids[p * N_EDGES + 0];
        const int c1 = cids[p * N_EDGES + 1];
        const int c2 = cids[p * N_EDGES + 2];
        const int c3 = cids[p * N_EDGES + 3];
        const f32x4* r0 = (const f32x4*)(node_mars + (size_t)c0 * BATCH);
        const f32x4* r1 = (const f32x4*)(node_mars + (size_t)c1 * BATCH);
        const f32x4* r2 = (const f32x4*)(node_mars + (size_t)c2 * BATCH);
        const f32x4* r3 = (const f32x4*)(node_mars + (size_t)c3 * BATCH);
        f32x4 a = r0[lane];
        f32x4 b = r1[lane];
        f32x4 c = r2[lane];
        f32x4 d = r3[lane];
        f32x4 s = (a + b) + (c + d);
        // non-temporal: output is write-once, never re-read by this kernel.
        // Keeps LLC capacity for node_mars gather reuse.
        __builtin_nontemporal_store(s, (f32x4*)(out + (size_t)out_row * BATCH) + lane);
    } else {
        // rows never targeted by the scatter (nids == arange(N_PROD)):
        // keep original element_mars values
        f32x4 v = ((const f32x4*)(element_mars + (size_t)p * BATCH))[lane];
        __builtin_nontemporal_store(v, (f32x4*)(out + (size_t)p * BATCH) + lane);
    }
}

extern "C" void kernel_launch(void* const* d_in, const int* in_sizes, int n_in,
                              void* d_out, int out_size, void* d_ws, size_t ws_size,
                              hipStream_t stream) {
    const float* node_mars    = (const float*)d_in[0];
    const float* element_mars = (const float*)d_in[1];
    const int*   nids         = (const int*)d_in[2];
    const int*   cids         = (const int*)d_in[3];
    float*       out          = (float*)d_out;

    const int nBlocks = (MAX_ELS + ROWS_PER_BLOCK - 1) / ROWS_PER_BLOCK;  // 32800
    ProdLayer_69750268887705_kernel<<<nBlocks, 256, 0, stream>>>(
        node_mars, element_mars, nids, cids, out);
}

// Round 4
// 95.945 us; speedup vs baseline: 1.0287x; 1.0287x over previous
//
#include <hip/hip_runtime.h>

// ProdLayer forward (block_size==1, single partition, accum=False):
//   element_mars[nids] = node_mars[cids].sum(axis=1)
// node_mars:    [131072, 512] f32 (268 MB)
// element_mars: [ 65600, 512] f32
// nids:         [65536]       int32 (arange; unique)
// cids:         [65536, 4]    int32 (random rows)
// out:          [ 65600, 512] f32 (134 MB, write-once)
//
// R1 (row-at-a-time, float4): 95.2 us ~= zero LLC reuse (full 537MB gather).
// R3 (NT stores): 98.7 us -> write pollution NOT the lever. Reverted.
// R4: batch-column chunking. 4 chunks x 128 cols; per-chunk node_mars
// working set = 67MB << 256MB LLC, so the 2x average row reuse dedups in
// LLC within a chunk phase. Grid is chunk-major so phases run ~sequentially
// (dispatch-order locality heuristic; output correctness is order-independent).

constexpr int BATCH    = 512;
constexpr int N_PROD   = 65536;
constexpr int MAX_ELS  = 65600;
constexpr int N_EDGES  = 4;
constexpr int CHUNKS   = 4;
constexpr int CHUNK_W  = BATCH / CHUNKS;        // 128 floats per chunk
constexpr int LANES    = CHUNK_W / 4;           // 32 float4 lanes per product
constexpr int PROD_PER_BLOCK = 256 / LANES;     // 8 products per 256-thr block
constexpr int BLOCKS_PER_CHUNK = MAX_ELS / PROD_PER_BLOCK;  // 8200 exactly

typedef float f32x4 __attribute__((ext_vector_type(4)));
typedef int   i32x4 __attribute__((ext_vector_type(4)));

__global__ __launch_bounds__(256) void ProdLayer_69750268887705_kernel(
    const float* __restrict__ node_mars,
    const float* __restrict__ element_mars,
    const int*   __restrict__ nids,
    const int*   __restrict__ cids,
    float*       __restrict__ out)
{
    const int tid  = threadIdx.x;
    const int lane = tid & (LANES - 1);          // float4 index within chunk
    const int psub = tid >> 5;                   // 0..7: product within block

    const int chunk = blockIdx.x / BLOCKS_PER_CHUNK;       // 0..3 (chunk-major)
    const int bic   = blockIdx.x - chunk * BLOCKS_PER_CHUNK;
    const int p     = bic * PROD_PER_BLOCK + psub;         // 0..65599

    // float4 offset of this thread's slice within a row
    const int col4 = chunk * (CHUNK_W / 4) + lane;         // 0..127

    if (p < N_PROD) {
        const int out_row = nids[p];
        const i32x4 c = *(const i32x4*)(cids + (size_t)p * N_EDGES);  // 16B aligned
        const f32x4 a = *((const f32x4*)(node_mars + (size_t)c.x * BATCH) + col4);
        const f32x4 b = *((const f32x4*)(node_mars + (size_t)c.y * BATCH) + col4);
        const f32x4 d = *((const f32x4*)(node_mars + (size_t)c.z * BATCH) + col4);
        const f32x4 e = *((const f32x4*)(node_mars + (size_t)c.w * BATCH) + col4);
        const f32x4 s = (a + b) + (d + e);
        *((f32x4*)(out + (size_t)out_row * BATCH) + col4) = s;
    } else {
        // rows never targeted by the scatter: keep element_mars values
        *((f32x4*)(out + (size_t)p * BATCH) + col4) =
            *((const f32x4*)(element_mars + (size_t)p * BATCH) + col4);
    }
}

extern "C" void kernel_launch(void* const* d_in, const int* in_sizes, int n_in,
                              void* d_out, int out_size, void* d_ws, size_t ws_size,
                              hipStream_t stream) {
    const float* node_mars    = (const float*)d_in[0];
    const float* element_mars = (const float*)d_in[1];
    const int*   nids         = (const int*)d_in[2];
    const int*   cids         = (const int*)d_in[3];
    float*       out          = (float*)d_out;

    const int nBlocks = CHUNKS * BLOCKS_PER_CHUNK;   // 32800
    ProdLayer_69750268887705_kernel<<<nBlocks, 256, 0, stream>>>(
        node_mars, element_mars, nids, cids, out);
}